// Round 6
// baseline (1444.677 us; speedup 1.0000x reference)
//
#include <hip/hip_runtime.h>
#include <cstdint>
#include <cstddef>

#define NN 100000
#define NE 1600000
#define NTOT (NE + NN)      // 1700000 edges incl self-loops
#define HF 128              // hidden features
#define OF 64               // output features
#define AGG_BLOCKS 1024

typedef float f4_t __attribute__((ext_vector_type(4)));   // nontemporal-store-able

// ---------------- helpers ----------------

__device__ __forceinline__ unsigned int f2bf_rne(float f) {
    unsigned int u = __float_as_uint(f);
    return (u + 0x7fffu + ((u >> 16) & 1u)) >> 16;
}
__device__ __forceinline__ unsigned int pack_bf2(float lo, float hi) {
    return f2bf_rne(lo) | (f2bf_rne(hi) << 16);
}

// ---------------- graph preprocessing ----------------

__global__ __launch_bounds__(256) void k_init(int* flag, int* deg) {
    int i = blockIdx.x * 256 + threadIdx.x;
    if (i == 0) *flag = 0;
    if (i < NN) deg[i] = 1;   // self-loop
}

// OR-reduce odd 32-bit words of edge_index: all zero <=> data is int64.
__global__ __launch_bounds__(256) void k_detect(const int* ei, int* flag) {
    int t = blockIdx.x * blockDim.x + threadIdx.x;
    int v = 0;
    for (int i = t; i < NE; i += gridDim.x * blockDim.x) v |= ei[2 * i + 1];
    unsigned long long b = __ballot(v != 0);
    if ((threadIdx.x & 63) == 0 && b) atomicOr(flag, 1);
}

__device__ __forceinline__ int edge_src(const int* ei, int e, bool is64) {
    return is64 ? ei[2 * e] : ei[e];
}
__device__ __forceinline__ int edge_dst(const int* ei, int e, bool is64) {
    return is64 ? ei[2 * (NE + e)] : ei[NE + e];
}

__global__ __launch_bounds__(256) void k_hist(const int* ei, const int* flag, int* deg) {
    int e = blockIdx.x * 256 + threadIdx.x;
    if (e >= NE) return;
    bool is64 = (*flag) == 0;
    atomicAdd(&deg[edge_dst(ei, e, is64)], 1);
}

// exclusive scan of deg[N] -> rowptr (partial), also dinv = rsqrt(deg)
__global__ __launch_bounds__(256) void k_scanA(const int* deg, int* rowptr, int* bsum,
                                               float* dinv) {
    __shared__ int sh[256];
    int tid = threadIdx.x;
    int base = blockIdx.x * 1024 + tid * 4;
    int v0 = 0, v1 = 0, v2 = 0, v3 = 0;
    if (base + 0 < NN) v0 = deg[base + 0];
    if (base + 1 < NN) v1 = deg[base + 1];
    if (base + 2 < NN) v2 = deg[base + 2];
    if (base + 3 < NN) v3 = deg[base + 3];
    if (base + 0 < NN) dinv[base + 0] = rsqrtf((float)v0);
    if (base + 1 < NN) dinv[base + 1] = rsqrtf((float)v1);
    if (base + 2 < NN) dinv[base + 2] = rsqrtf((float)v2);
    if (base + 3 < NN) dinv[base + 3] = rsqrtf((float)v3);
    int s = v0 + v1 + v2 + v3;
    sh[tid] = s;
    __syncthreads();
    for (int off = 1; off < 256; off <<= 1) {
        int t = (tid >= off) ? sh[tid - off] : 0;
        __syncthreads();
        sh[tid] += t;
        __syncthreads();
    }
    int run = sh[tid] - s;
    if (base + 0 < NN) rowptr[base + 0] = run; run += v0;
    if (base + 1 < NN) rowptr[base + 1] = run; run += v1;
    if (base + 2 < NN) rowptr[base + 2] = run; run += v2;
    if (base + 3 < NN) rowptr[base + 3] = run;
    if (tid == 255) bsum[blockIdx.x] = sh[255];
}

__global__ __launch_bounds__(128) void k_scanB(const int* bsum, int* boff, int* rowptr) {
    __shared__ int sh[128];
    int tid = threadIdx.x;
    int v = (tid < 98) ? bsum[tid] : 0;
    sh[tid] = v;
    __syncthreads();
    for (int off = 1; off < 128; off <<= 1) {
        int t = (tid >= off) ? sh[tid - off] : 0;
        __syncthreads();
        sh[tid] += t;
        __syncthreads();
    }
    if (tid < 98) boff[tid] = sh[tid] - v;
    if (tid == 0) rowptr[NN] = NTOT;
}

__global__ __launch_bounds__(256) void k_scanC(int* rowptr, const int* boff, int* cursor) {
    int i = blockIdx.x * 256 + threadIdx.x;
    if (i < NN) {
        int r = rowptr[i] + boff[i >> 10];
        rowptr[i] = r;
        cursor[i] = r;
    }
}

__global__ __launch_bounds__(256) void k_scatter(const int* ei, const int* flag,
                                                 int* cursor, int* csr) {
    int e = blockIdx.x * 256 + threadIdx.x;
    if (e >= NTOT) return;
    bool is64 = (*flag) == 0;
    int s, d;
    if (e < NE) { s = edge_src(ei, e, is64); d = edge_dst(ei, e, is64); }
    else        { s = e - NE; d = s; }
    int pos = atomicAdd(&cursor[d], 1);
    csr[pos] = s;
}

// ---------------- dense compute ----------------

// m layout is CHUNK-MAJOR: chunk c (16 feats) = m[c*NN*8 .. ], row r at +r*8 uints.
// Fused: m[c][r]       = bf16( dinv[r] * (A[r][:] @ W) )  chunked bf16
//        logits[r][:] (+)= A[r][:] @ Wjk (+ linb if first)
__global__ __launch_bounds__(256) void k_mmf(const float* __restrict__ A,
                                             const float* __restrict__ W,
                                             const float* __restrict__ dinv,
                                             const float* __restrict__ Wjk,
                                             const float* __restrict__ linb,
                                             float* __restrict__ logits, int first,
                                             unsigned int* __restrict__ m) {
    __shared__ float At[32][68];    // transposed: At[k][r]
    __shared__ float Wt[32][128];
    __shared__ float Wjt[32][64];
    int tid = threadIdx.x;
    int tx = tid & 31, ty = tid >> 5;
    int row0 = blockIdx.x * 64;
    bool has_jk = (Wjk != nullptr);

    float acc[8][4];
    float accj[8][2];
#pragma unroll
    for (int j = 0; j < 8; ++j) {
#pragma unroll
        for (int c = 0; c < 4; ++c) acc[j][c] = 0.f;
        accj[j][0] = accj[j][1] = 0.f;
    }

    for (int kb = 0; kb < 128; kb += 32) {
#pragma unroll
        for (int i = 0; i < 4; ++i) {                 // W chunk 32x128
            int kr = ty + i * 8;
            float4 wv = *(const float4*)&W[(size_t)(kb + kr) * 128 + tx * 4];
            *(float4*)&Wt[kr][tx * 4] = wv;
        }
        if (has_jk) {
#pragma unroll
            for (int i = 0; i < 4; ++i) {             // Wjk chunk 32x64
                int kr = ty + i * 8;
                float2 wv = *(const float2*)&Wjk[(size_t)(kb + kr) * 64 + tx * 2];
                *(float2*)&Wjt[kr][tx * 2] = wv;
            }
        }
#pragma unroll
        for (int i = 0; i < 2; ++i) {                 // A chunk 64x32, transposed store
            int idx = tid + i * 256;
            int r = idx >> 3, c4 = idx & 7;
            int gr = row0 + r;
            float4 v = make_float4(0.f, 0.f, 0.f, 0.f);
            if (gr < NN) v = *(const float4*)&A[(size_t)gr * 128 + kb + c4 * 4];
            At[c4 * 4 + 0][r] = v.x;
            At[c4 * 4 + 1][r] = v.y;
            At[c4 * 4 + 2][r] = v.z;
            At[c4 * 4 + 3][r] = v.w;
        }
        __syncthreads();
#pragma unroll 4
        for (int k = 0; k < 32; ++k) {
            float4 a0 = *(const float4*)&At[k][ty * 8];
            float4 a1 = *(const float4*)&At[k][ty * 8 + 4];
            float4 wv = *(const float4*)&Wt[k][tx * 4];
            float a[8] = {a0.x, a0.y, a0.z, a0.w, a1.x, a1.y, a1.z, a1.w};
#pragma unroll
            for (int j = 0; j < 8; ++j) {
                acc[j][0] += a[j] * wv.x;
                acc[j][1] += a[j] * wv.y;
                acc[j][2] += a[j] * wv.z;
                acc[j][3] += a[j] * wv.w;
            }
            if (has_jk) {
                float2 wj = *(const float2*)&Wjt[k][tx * 2];
#pragma unroll
                for (int j = 0; j < 8; ++j) {
                    accj[j][0] += a[j] * wj.x;
                    accj[j][1] += a[j] * wj.y;
                }
            }
        }
        __syncthreads();
    }
    // chunk-major m write: thread tx owns feats tx*4..tx*4+3 -> chunk tx>>2
    unsigned int* mcb = m + (size_t)(tx >> 2) * NN * 8 + (size_t)(tx & 3) * 2;
#pragma unroll
    for (int j = 0; j < 8; ++j) {
        int r = row0 + ty * 8 + j;
        if (r < NN) {
            float sc = dinv[r];
            uint2 o;
            o.x = pack_bf2(acc[j][0] * sc, acc[j][1] * sc);
            o.y = pack_bf2(acc[j][2] * sc, acc[j][3] * sc);
            *(uint2*)(mcb + (size_t)r * 8) = o;
            if (has_jk) {
                float2 prev;
                if (first) prev = *(const float2*)&linb[tx * 2];
                else       prev = *(const float2*)&logits[(size_t)r * 64 + tx * 2];
                float2 ov = make_float2(prev.x + accj[j][0], prev.y + accj[j][1]);
                *(float2*)&logits[(size_t)r * 64 + tx * 2] = ov;
            }
        }
    }
}

// Chunked aggregation: out[d][:] = relu(dinv[d]*sum_{s in N(d)} m[s][:] + b).
// Persistent grid sweeps 8 feature-chunks; each 3.2 MB chunk is L2-resident
// (replicated per XCD). 4 lanes per node; uint2 (8 B) per lane = 32 B row-chunk;
// per group the 16-f32 output is exactly one 64 B line (full-line store).
// csr via nontemporal loads, out via nontemporal stores (preserve chunk residency).
__global__ __launch_bounds__(256) void k_aggc(const int* __restrict__ rowptr,
                                              const int* __restrict__ csr,
                                              const unsigned int* __restrict__ m,
                                              const float* __restrict__ dinv,
                                              const float* __restrict__ bias,
                                              float* __restrict__ out) {
    int tid = threadIdx.x;
    int lane4 = tid & 3, grp = tid >> 2;       // 64 groups per block
    for (int c = 0; c < 8; ++c) {
        const uint2* __restrict__ mb = (const uint2*)(m + (size_t)c * NN * 8);
        float4 bb = *(const float4*)&bias[c * 16 + lane4 * 4];
        for (int node = blockIdx.x * 64 + grp; node < NN; node += AGG_BLOCKS * 64) {
            int beg = rowptr[node], end = rowptr[node + 1];
            float f0 = 0.f, f1 = 0.f, f2 = 0.f, f3 = 0.f;
            int e = beg;
            for (; e + 4 <= end; e += 4) {
                int s0 = __builtin_nontemporal_load(&csr[e]);
                int s1 = __builtin_nontemporal_load(&csr[e + 1]);
                int s2 = __builtin_nontemporal_load(&csr[e + 2]);
                int s3 = __builtin_nontemporal_load(&csr[e + 3]);
                uint2 v0 = mb[(size_t)s0 * 4 + lane4];
                uint2 v1 = mb[(size_t)s1 * 4 + lane4];
                uint2 v2 = mb[(size_t)s2 * 4 + lane4];
                uint2 v3 = mb[(size_t)s3 * 4 + lane4];
                f0 += __uint_as_float(v0.x << 16) + __uint_as_float(v1.x << 16)
                    + __uint_as_float(v2.x << 16) + __uint_as_float(v3.x << 16);
                f1 += __uint_as_float(v0.x & 0xffff0000u) + __uint_as_float(v1.x & 0xffff0000u)
                    + __uint_as_float(v2.x & 0xffff0000u) + __uint_as_float(v3.x & 0xffff0000u);
                f2 += __uint_as_float(v0.y << 16) + __uint_as_float(v1.y << 16)
                    + __uint_as_float(v2.y << 16) + __uint_as_float(v3.y << 16);
                f3 += __uint_as_float(v0.y & 0xffff0000u) + __uint_as_float(v1.y & 0xffff0000u)
                    + __uint_as_float(v2.y & 0xffff0000u) + __uint_as_float(v3.y & 0xffff0000u);
            }
            for (; e < end; ++e) {
                int s = __builtin_nontemporal_load(&csr[e]);
                uint2 v = mb[(size_t)s * 4 + lane4];
                f0 += __uint_as_float(v.x << 16);
                f1 += __uint_as_float(v.x & 0xffff0000u);
                f2 += __uint_as_float(v.y << 16);
                f3 += __uint_as_float(v.y & 0xffff0000u);
            }
            float sc = dinv[node];
            f4_t o;
            o.x = fmaxf(f0 * sc + bb.x, 0.f);
            o.y = fmaxf(f1 * sc + bb.y, 0.f);
            o.z = fmaxf(f2 * sc + bb.z, 0.f);
            o.w = fmaxf(f3 * sc + bb.w, 0.f);
            __builtin_nontemporal_store(o,
                (f4_t*)&out[(size_t)node * 128 + c * 16 + lane4 * 4]);
        }
    }
}

// Final: logits[r][:] += H[r][:] @ Wl; then in-place log_softmax.
__global__ __launch_bounds__(256) void k_jk_lsm(const float* __restrict__ Hl,
                                                const float* __restrict__ Wl,
                                                float* __restrict__ logits) {
    __shared__ float At[32][68];
    __shared__ float Wt[32][64];
    int tid = threadIdx.x;
    int tx = tid & 15, ty = tid >> 4;
    int row0 = blockIdx.x * 64;
    float acc[4][4];
#pragma unroll
    for (int j = 0; j < 4; ++j)
#pragma unroll
        for (int c = 0; c < 4; ++c) acc[j][c] = 0.f;

    for (int kb = 0; kb < 128; kb += 32) {
#pragma unroll
        for (int i = 0; i < 2; ++i) {                 // Wl chunk 32x64
            int kr = ty + i * 16;
            float4 wv = *(const float4*)&Wl[(size_t)(kb + kr) * 64 + tx * 4];
            *(float4*)&Wt[kr][tx * 4] = wv;
        }
#pragma unroll
        for (int i = 0; i < 2; ++i) {                 // A chunk 64x32, transposed
            int idx = tid + i * 256;
            int r = idx >> 3, c4 = idx & 7;
            int gr = row0 + r;
            float4 v = make_float4(0.f, 0.f, 0.f, 0.f);
            if (gr < NN) v = *(const float4*)&Hl[(size_t)gr * 128 + kb + c4 * 4];
            At[c4 * 4 + 0][r] = v.x;
            At[c4 * 4 + 1][r] = v.y;
            At[c4 * 4 + 2][r] = v.z;
            At[c4 * 4 + 3][r] = v.w;
        }
        __syncthreads();
#pragma unroll 4
        for (int k = 0; k < 32; ++k) {
            float4 a4 = *(const float4*)&At[k][ty * 4];
            float4 wv = *(const float4*)&Wt[k][tx * 4];
            float a[4] = {a4.x, a4.y, a4.z, a4.w};
#pragma unroll
            for (int j = 0; j < 4; ++j) {
                acc[j][0] += a[j] * wv.x;
                acc[j][1] += a[j] * wv.y;
                acc[j][2] += a[j] * wv.z;
                acc[j][3] += a[j] * wv.w;
            }
        }
        __syncthreads();
    }
#pragma unroll
    for (int j = 0; j < 4; ++j) {
        int r = row0 + ty * 4 + j;
        if (r < NN) {
            float4 prev = *(const float4*)&logits[(size_t)r * 64 + tx * 4];
            float v0 = prev.x + acc[j][0];
            float v1 = prev.y + acc[j][1];
            float v2 = prev.z + acc[j][2];
            float v3 = prev.w + acc[j][3];
            float mx = fmaxf(fmaxf(v0, v1), fmaxf(v2, v3));
#pragma unroll
            for (int s = 1; s < 16; s <<= 1) mx = fmaxf(mx, __shfl_xor(mx, s, 16));
            float e0 = expf(v0 - mx), e1 = expf(v1 - mx);
            float e2 = expf(v2 - mx), e3 = expf(v3 - mx);
            float sum = (e0 + e1) + (e2 + e3);
#pragma unroll
            for (int s = 1; s < 16; s <<= 1) sum += __shfl_xor(sum, s, 16);
            float ls = logf(sum) + mx;
            float4 o = make_float4(v0 - ls, v1 - ls, v2 - ls, v3 - ls);
            *(float4*)&logits[(size_t)r * 64 + tx * 4] = o;
        }
    }
}

// ---------------- launch ----------------

extern "C" void kernel_launch(void* const* d_in, const int* in_sizes, int n_in,
                              void* d_out, int out_size, void* d_ws, size_t ws_size,
                              hipStream_t stream) {
    const float* x    = (const float*)d_in[0];
    const int*   ei   = (const int*)d_in[1];
    const float* W[4] = {(const float*)d_in[2], (const float*)d_in[4],
                         (const float*)d_in[6], (const float*)d_in[8]};
    const float* b[4] = {(const float*)d_in[3], (const float*)d_in[5],
                         (const float*)d_in[7], (const float*)d_in[9]};
    const float* linW = (const float*)d_in[10];
    const float* linb = (const float*)d_in[11];
    float* out = (float*)d_out;

    char* wp = (char*)d_ws;
    auto alloc = [&](size_t bytes) {
        void* p = (void*)wp;
        wp += (bytes + 255) & ~(size_t)255;
        return p;
    };
    int*   flag   = (int*)  alloc(4);
    int*   deg    = (int*)  alloc((size_t)NN * 4);
    float* dinv   = (float*)alloc((size_t)NN * 4);
    int*   rowptr = (int*)  alloc((size_t)(NN + 1) * 4);
    int*   cursor = (int*)  alloc((size_t)NN * 4);
    int*   bsum   = (int*)  alloc(512);
    int*   boff   = (int*)  alloc(512);
    int*   csr    = (int*)  alloc((size_t)NTOT * 4);
    unsigned int* bufM = (unsigned int*)alloc((size_t)NN * 64 * 4);  // bf16, chunk-major
    float* bufB   = (float*)alloc((size_t)NN * HF * 4);
    float* bufC   = (float*)alloc((size_t)NN * HF * 4);

    dim3 blk(256);
    k_init   <<<391, blk, 0, stream>>>(flag, deg);
    k_detect <<<1024, blk, 0, stream>>>(ei, flag);
    k_hist   <<<6250, blk, 0, stream>>>(ei, flag, deg);
    k_scanA  <<<98, blk, 0, stream>>>(deg, rowptr, bsum, dinv);
    k_scanB  <<<1, dim3(128), 0, stream>>>(bsum, boff, rowptr);
    k_scanC  <<<391, blk, 0, stream>>>(rowptr, boff, cursor);
    k_scatter<<<6641, blk, 0, stream>>>(ei, flag, cursor, csr);

    const float* lin[4]  = {x, bufB, bufC, bufB};
    float*       lout[4] = {bufB, bufC, bufB, bufC};
    for (int l = 0; l < 4; ++l) {
        const float* wjk = (l == 0) ? nullptr : linW + (size_t)(l - 1) * 128 * 64;
        k_mmf<<<1563, blk, 0, stream>>>(lin[l], W[l], dinv, wjk, linb, out,
                                        l == 1 ? 1 : 0, bufM);
        k_aggc<<<AGG_BLOCKS, blk, 0, stream>>>(rowptr, csr, bufM, dinv,
                                               b[l], lout[l]);
    }
    k_jk_lsm<<<1563, blk, 0, stream>>>(lout[3], linW + (size_t)3 * 128 * 64, out);
}

// Round 7
// 694.197 us; speedup vs baseline: 2.0811x; 2.0811x over previous
//
#include <hip/hip_runtime.h>
#include <cstdint>
#include <cstddef>

#define NN 100000
#define NE 1600000
#define NTOT (NE + NN)      // 1700000 edges incl self-loops
#define HF 128              // hidden features
#define OF 64               // output features

typedef short bfrag_t __attribute__((ext_vector_type(8)));   // 8 bf16 = 4 VGPR
typedef float f4v     __attribute__((ext_vector_type(4)));   // MFMA acc

// ---------------- helpers ----------------

__device__ __forceinline__ unsigned int f2bf_rne(float f) {
    unsigned int u = __float_as_uint(f);
    return (u + 0x7fffu + ((u >> 16) & 1u)) >> 16;
}
__device__ __forceinline__ unsigned int pack_bf2(float lo, float hi) {
    return f2bf_rne(lo) | (f2bf_rne(hi) << 16);
}

// ---------------- graph preprocessing ----------------

__global__ __launch_bounds__(256) void k_init(int* flag, int* deg) {
    int i = blockIdx.x * 256 + threadIdx.x;
    if (i == 0) *flag = 0;
    if (i < NN) deg[i] = 1;   // self-loop
}

// OR-reduce odd 32-bit words of edge_index: all zero <=> data is int64.
__global__ __launch_bounds__(256) void k_detect(const int* ei, int* flag) {
    int t = blockIdx.x * blockDim.x + threadIdx.x;
    int v = 0;
    for (int i = t; i < NE; i += gridDim.x * blockDim.x) v |= ei[2 * i + 1];
    unsigned long long b = __ballot(v != 0);
    if ((threadIdx.x & 63) == 0 && b) atomicOr(flag, 1);
}

__device__ __forceinline__ int edge_src(const int* ei, int e, bool is64) {
    return is64 ? ei[2 * e] : ei[e];
}
__device__ __forceinline__ int edge_dst(const int* ei, int e, bool is64) {
    return is64 ? ei[2 * (NE + e)] : ei[NE + e];
}

__global__ __launch_bounds__(256) void k_hist(const int* ei, const int* flag, int* deg) {
    int e = blockIdx.x * 256 + threadIdx.x;
    if (e >= NE) return;
    bool is64 = (*flag) == 0;
    atomicAdd(&deg[edge_dst(ei, e, is64)], 1);
}

// exclusive scan of deg[N] -> rowptr (partial), also dinv = rsqrt(deg)
__global__ __launch_bounds__(256) void k_scanA(const int* deg, int* rowptr, int* bsum,
                                               float* dinv) {
    __shared__ int sh[256];
    int tid = threadIdx.x;
    int base = blockIdx.x * 1024 + tid * 4;
    int v0 = 0, v1 = 0, v2 = 0, v3 = 0;
    if (base + 0 < NN) v0 = deg[base + 0];
    if (base + 1 < NN) v1 = deg[base + 1];
    if (base + 2 < NN) v2 = deg[base + 2];
    if (base + 3 < NN) v3 = deg[base + 3];
    if (base + 0 < NN) dinv[base + 0] = rsqrtf((float)v0);
    if (base + 1 < NN) dinv[base + 1] = rsqrtf((float)v1);
    if (base + 2 < NN) dinv[base + 2] = rsqrtf((float)v2);
    if (base + 3 < NN) dinv[base + 3] = rsqrtf((float)v3);
    int s = v0 + v1 + v2 + v3;
    sh[tid] = s;
    __syncthreads();
    for (int off = 1; off < 256; off <<= 1) {
        int t = (tid >= off) ? sh[tid - off] : 0;
        __syncthreads();
        sh[tid] += t;
        __syncthreads();
    }
    int run = sh[tid] - s;
    if (base + 0 < NN) rowptr[base + 0] = run; run += v0;
    if (base + 1 < NN) rowptr[base + 1] = run; run += v1;
    if (base + 2 < NN) rowptr[base + 2] = run; run += v2;
    if (base + 3 < NN) rowptr[base + 3] = run;
    if (tid == 255) bsum[blockIdx.x] = sh[255];
}

__global__ __launch_bounds__(128) void k_scanB(const int* bsum, int* boff, int* rowptr) {
    __shared__ int sh[128];
    int tid = threadIdx.x;
    int v = (tid < 98) ? bsum[tid] : 0;
    sh[tid] = v;
    __syncthreads();
    for (int off = 1; off < 128; off <<= 1) {
        int t = (tid >= off) ? sh[tid - off] : 0;
        __syncthreads();
        sh[tid] += t;
        __syncthreads();
    }
    if (tid < 98) boff[tid] = sh[tid] - v;
    if (tid == 0) rowptr[NN] = NTOT;
}

__global__ __launch_bounds__(256) void k_scanC(int* rowptr, const int* boff, int* cursor) {
    int i = blockIdx.x * 256 + threadIdx.x;
    if (i < NN) {
        int r = rowptr[i] + boff[i >> 10];
        rowptr[i] = r;
        cursor[i] = r;
    }
}

__global__ __launch_bounds__(256) void k_scatter(const int* ei, const int* flag,
                                                 int* cursor, int* csr) {
    int e = blockIdx.x * 256 + threadIdx.x;
    if (e >= NTOT) return;
    bool is64 = (*flag) == 0;
    int s, d;
    if (e < NE) { s = edge_src(ei, e, is64); d = edge_dst(ei, e, is64); }
    else        { s = e - NE; d = s; }
    int pos = atomicAdd(&cursor[d], 1);
    csr[pos] = s;
}

// ---------------- weight prep: bf16 + transpose to [n][k] ----------------
// WT[l][n*128+k]  = bf16(W_l[k][n])        (4 x 128x128)
// WjT[l][n*128+k] = bf16(linW[l*128+k][n]) (4 x 64x128)
__global__ __launch_bounds__(256) void k_prep(const float* __restrict__ W0,
                                              const float* __restrict__ W1,
                                              const float* __restrict__ W2,
                                              const float* __restrict__ W3,
                                              const float* __restrict__ linW,
                                              unsigned short* __restrict__ WT,
                                              unsigned short* __restrict__ WjT) {
    int idx = blockIdx.x * 256 + threadIdx.x;
    if (idx < 4 * 128 * 128) {
        int l = idx >> 14, r = idx & 16383, n = r >> 7, k = r & 127;
        const float* Wl = (l == 0) ? W0 : (l == 1) ? W1 : (l == 2) ? W2 : W3;
        WT[idx] = (unsigned short)f2bf_rne(Wl[k * 128 + n]);
    } else if (idx < 4 * 128 * 128 + 4 * 64 * 128) {
        int i2 = idx - 65536;
        int l = i2 >> 13, r = i2 & 8191, n = r >> 7, k = r & 127;
        WjT[i2] = (unsigned short)f2bf_rne(linW[(size_t)(l * 128 + k) * 64 + n]);
    }
}

// ---------------- MFMA matmul + fused JK ----------------
// m16[r][:]     = bf16( dinv[r] * (A[r][:] @ W) )          [N][128] bf16 row-major
// logits[r][:] (+)= A[r][:] @ Wjk (+ linb if first)         [N][64] f32   (if WjT)
// 64-row tile, 4 waves; wave w owns rows [16w,16w+16). 16x16x32 bf16 MFMA.
// Fragment layout (m89/m91-verified family): A row=lane&15, k=(lane>>4)*8+i;
// B(col-major operand [n][k]) col=lane&15, same k; D col=lane&15, row=(lane>>4)*4+reg.
// LDS XOR swizzle byte^=((row&7)<<4) kills the stride-256B 16-way bank conflict.
__global__ __launch_bounds__(256) void k_mmf(const float* __restrict__ A,
                                             const unsigned short* __restrict__ WT,
                                             const float* __restrict__ dinv,
                                             const unsigned short* __restrict__ WjT,
                                             const float* __restrict__ linb,
                                             float* __restrict__ logits, int first,
                                             unsigned short* __restrict__ m16) {
    __shared__ unsigned short Alds[64 * 128];    // 16 KB
    __shared__ unsigned short Wlds[128 * 128];   // 32 KB
    __shared__ unsigned short Wjlds[64 * 128];   // 16 KB
    int tid = threadIdx.x;
    int row0 = blockIdx.x * 64;
    bool has_jk = (WjT != nullptr);

    // stage W^T (128 rows x 128 bf16), swizzled
    for (int c = tid; c < 2048; c += 256) {
        int row = c >> 4, c16 = c & 15;
        uint4 v = *(const uint4*)&WT[row * 128 + c16 * 8];
        *(uint4*)((char*)Wlds + row * 256 + ((c16 * 16) ^ ((row & 7) << 4))) = v;
    }
    if (has_jk) {
        for (int c = tid; c < 1024; c += 256) {
            int row = c >> 4, c16 = c & 15;
            uint4 v = *(const uint4*)&WjT[row * 128 + c16 * 8];
            *(uint4*)((char*)Wjlds + row * 256 + ((c16 * 16) ^ ((row & 7) << 4))) = v;
        }
    }
    // stage A (64 rows x 128 f32 -> bf16), swizzled
    {
        int row = tid >> 2, gr = row0 + row;
#pragma unroll
        for (int j = 0; j < 4; ++j) {
            int c8 = (tid & 3) * 4 + j;
            float4 v0 = make_float4(0.f, 0.f, 0.f, 0.f);
            float4 v1 = make_float4(0.f, 0.f, 0.f, 0.f);
            if (gr < NN) {
                v0 = *(const float4*)&A[(size_t)gr * 128 + c8 * 8];
                v1 = *(const float4*)&A[(size_t)gr * 128 + c8 * 8 + 4];
            }
            uint4 o;
            o.x = pack_bf2(v0.x, v0.y);
            o.y = pack_bf2(v0.z, v0.w);
            o.z = pack_bf2(v1.x, v1.y);
            o.w = pack_bf2(v1.z, v1.w);
            *(uint4*)((char*)Alds + row * 256 + ((c8 * 16) ^ ((row & 7) << 4))) = o;
        }
    }
    __syncthreads();

    int lane = tid & 63, w = tid >> 6;
    int r15 = lane & 15, q = lane >> 4;
    int xo = (r15 & 7) << 4;

    f4v acc[8], accj[4];
#pragma unroll
    for (int i = 0; i < 8; ++i) acc[i] = (f4v){0.f, 0.f, 0.f, 0.f};
#pragma unroll
    for (int i = 0; i < 4; ++i) accj[i] = (f4v){0.f, 0.f, 0.f, 0.f};

#pragma unroll
    for (int ks = 0; ks < 4; ++ks) {
        int ko = ks * 64 + q * 16;
        bfrag_t a = *(const bfrag_t*)((const char*)Alds + (16 * w + r15) * 256 + (ko ^ xo));
#pragma unroll
        for (int nb = 0; nb < 8; ++nb) {
            bfrag_t b = *(const bfrag_t*)((const char*)Wlds + (nb * 16 + r15) * 256 + (ko ^ xo));
            acc[nb] = __builtin_amdgcn_mfma_f32_16x16x32_bf16(a, b, acc[nb], 0, 0, 0);
        }
        if (has_jk) {
#pragma unroll
            for (int jb = 0; jb < 4; ++jb) {
                bfrag_t b = *(const bfrag_t*)((const char*)Wjlds + (jb * 16 + r15) * 256 + (ko ^ xo));
                accj[jb] = __builtin_amdgcn_mfma_f32_16x16x32_bf16(a, b, accj[jb], 0, 0, 0);
            }
        }
    }

#pragma unroll
    for (int reg = 0; reg < 4; ++reg) {
        int gr = row0 + 16 * w + q * 4 + reg;
        if (gr < NN) {
            float sc = dinv[gr];
#pragma unroll
            for (int nb = 0; nb < 8; ++nb)
                m16[(size_t)gr * 128 + nb * 16 + r15] =
                    (unsigned short)f2bf_rne(acc[nb][reg] * sc);
            if (has_jk) {
#pragma unroll
                for (int jb = 0; jb < 4; ++jb) {
                    size_t off = (size_t)gr * 64 + jb * 16 + r15;
                    float prev = first ? linb[jb * 16 + r15] : logits[off];
                    logits[off] = prev + accj[jb][reg];
                }
            }
        }
    }
}

// h_out[d][:] = relu(dinv[d] * sum_{s in N(d)} bf16m[s][:] + b)
// one wave per node; 4 groups of 16 lanes; group g gathers a full 256 B row
// (16 B/lane). All __shfl ops executed by ALL 64 lanes (wave-uniform context).
__global__ __launch_bounds__(256) void k_agg(const int* __restrict__ rowptr,
                                             const int* __restrict__ csr,
                                             const uint4* __restrict__ m4,
                                             const float* __restrict__ dinv,
                                             const float* __restrict__ bias,
                                             float* __restrict__ out) {
    int w = threadIdx.x >> 6, lane = threadIdx.x & 63;
    int grp = lane >> 4, lj = lane & 15;
    int node = blockIdx.x * 4 + w;
    if (node >= NN) return;
    int beg = rowptr[node], end = rowptr[node + 1];

    float a[8];
#pragma unroll
    for (int q = 0; q < 8; ++q) a[q] = 0.f;

    for (int base = beg; base < end; base += 64) {
        int cnt = min(64, end - base);
        int sv = (lane < cnt) ? csr[base + lane] : 0;
        int k = 0;
        for (; k + 8 <= cnt; k += 8) {
            int sA = __shfl(sv, k + grp);
            int sB = __shfl(sv, k + 4 + grp);
            uint4 vA = m4[(size_t)sA * 16 + lj];
            uint4 vB = m4[(size_t)sB * 16 + lj];
            a[0] += __uint_as_float(vA.x << 16);
            a[1] += __uint_as_float(vA.x & 0xffff0000u);
            a[2] += __uint_as_float(vA.y << 16);
            a[3] += __uint_as_float(vA.y & 0xffff0000u);
            a[4] += __uint_as_float(vA.z << 16);
            a[5] += __uint_as_float(vA.z & 0xffff0000u);
            a[6] += __uint_as_float(vA.w << 16);
            a[7] += __uint_as_float(vA.w & 0xffff0000u);
            a[0] += __uint_as_float(vB.x << 16);
            a[1] += __uint_as_float(vB.x & 0xffff0000u);
            a[2] += __uint_as_float(vB.y << 16);
            a[3] += __uint_as_float(vB.y & 0xffff0000u);
            a[4] += __uint_as_float(vB.z << 16);
            a[5] += __uint_as_float(vB.z & 0xffff0000u);
            a[6] += __uint_as_float(vB.w << 16);
            a[7] += __uint_as_float(vB.w & 0xffff0000u);
        }
        if (k + 4 <= cnt) {       // wave-uniform; all lanes shuffle
            int s = __shfl(sv, k + grp);
            uint4 v = m4[(size_t)s * 16 + lj];
            a[0] += __uint_as_float(v.x << 16);
            a[1] += __uint_as_float(v.x & 0xffff0000u);
            a[2] += __uint_as_float(v.y << 16);
            a[3] += __uint_as_float(v.y & 0xffff0000u);
            a[4] += __uint_as_float(v.z << 16);
            a[5] += __uint_as_float(v.z & 0xffff0000u);
            a[6] += __uint_as_float(v.w << 16);
            a[7] += __uint_as_float(v.w & 0xffff0000u);
            k += 4;
        }
        int rem = cnt - k;              // 0..3
        if (rem) {                      // wave-uniform
            int idx = k + grp;
            if (idx >= cnt) idx = cnt - 1;   // clamp; shuffle by ALL lanes
            int s = __shfl(sv, idx);
            if (grp < rem) {            // only the accumulate is predicated
                uint4 v = m4[(size_t)s * 16 + lj];
                a[0] += __uint_as_float(v.x << 16);
                a[1] += __uint_as_float(v.x & 0xffff0000u);
                a[2] += __uint_as_float(v.y << 16);
                a[3] += __uint_as_float(v.y & 0xffff0000u);
                a[4] += __uint_as_float(v.z << 16);
                a[5] += __uint_as_float(v.z & 0xffff0000u);
                a[6] += __uint_as_float(v.w << 16);
                a[7] += __uint_as_float(v.w & 0xffff0000u);
            }
        }
    }
#pragma unroll
    for (int q = 0; q < 8; ++q) a[q] += __shfl_xor(a[q], 16);
#pragma unroll
    for (int q = 0; q < 8; ++q) a[q] += __shfl_xor(a[q], 32);

    float sc = dinv[node];
    if (grp == 0) {
        float4 bb = ((const float4*)bias)[lj * 2];
        float4 o = make_float4(fmaxf(a[0] * sc + bb.x, 0.f),
                               fmaxf(a[1] * sc + bb.y, 0.f),
                               fmaxf(a[2] * sc + bb.z, 0.f),
                               fmaxf(a[3] * sc + bb.w, 0.f));
        *(float4*)&out[(size_t)node * 128 + lj * 8] = o;
    } else if (grp == 1) {
        float4 bb = ((const float4*)bias)[lj * 2 + 1];
        float4 o = make_float4(fmaxf(a[4] * sc + bb.x, 0.f),
                               fmaxf(a[5] * sc + bb.y, 0.f),
                               fmaxf(a[6] * sc + bb.z, 0.f),
                               fmaxf(a[7] * sc + bb.w, 0.f));
        *(float4*)&out[(size_t)node * 128 + lj * 8 + 4] = o;
    }
}

// Final: logits[r][:] += H[r][:] @ Wl; then in-place log_softmax (width-16 shfl).
__global__ __launch_bounds__(256) void k_jk_lsm(const float* __restrict__ Hl,
                                                const float* __restrict__ Wl,
                                                float* __restrict__ logits) {
    __shared__ float At[32][68];
    __shared__ float Wt[32][64];
    int tid = threadIdx.x;
    int tx = tid & 15, ty = tid >> 4;
    int row0 = blockIdx.x * 64;
    float acc[4][4];
#pragma unroll
    for (int j = 0; j < 4; ++j)
#pragma unroll
        for (int c = 0; c < 4; ++c) acc[j][c] = 0.f;

    for (int kb = 0; kb < 128; kb += 32) {
#pragma unroll
        for (int i = 0; i < 2; ++i) {                 // Wl chunk 32x64
            int kr = ty + i * 16;
            float4 wv = *(const float4*)&Wl[(size_t)(kb + kr) * 64 + tx * 4];
            *(float4*)&Wt[kr][tx * 4] = wv;
        }
#pragma unroll
        for (int i = 0; i < 2; ++i) {                 // A chunk 64x32, transposed
            int idx = tid + i * 256;
            int r = idx >> 3, c4 = idx & 7;
            int gr = row0 + r;
            float4 v = make_float4(0.f, 0.f, 0.f, 0.f);
            if (gr < NN) v = *(const float4*)&Hl[(size_t)gr * 128 + kb + c4 * 4];
            At[c4 * 4 + 0][r] = v.x;
            At[c4 * 4 + 1][r] = v.y;
            At[c4 * 4 + 2][r] = v.z;
            At[c4 * 4 + 3][r] = v.w;
        }
        __syncthreads();
#pragma unroll 4
        for (int k = 0; k < 32; ++k) {
            float4 a4 = *(const float4*)&At[k][ty * 4];
            float4 wv = *(const float4*)&Wt[k][tx * 4];
            float a[4] = {a4.x, a4.y, a4.z, a4.w};
#pragma unroll
            for (int j = 0; j < 4; ++j) {
                acc[j][0] += a[j] * wv.x;
                acc[j][1] += a[j] * wv.y;
                acc[j][2] += a[j] * wv.z;
                acc[j][3] += a[j] * wv.w;
            }
        }
        __syncthreads();
    }
#pragma unroll
    for (int j = 0; j < 4; ++j) {
        int r = row0 + ty * 4 + j;
        if (r < NN) {
            float4 prev = *(const float4*)&logits[(size_t)r * 64 + tx * 4];
            float v0 = prev.x + acc[j][0];
            float v1 = prev.y + acc[j][1];
            float v2 = prev.z + acc[j][2];
            float v3 = prev.w + acc[j][3];
            float mx = fmaxf(fmaxf(v0, v1), fmaxf(v2, v3));
#pragma unroll
            for (int s = 1; s < 16; s <<= 1) mx = fmaxf(mx, __shfl_xor(mx, s, 16));
            float e0 = expf(v0 - mx), e1 = expf(v1 - mx);
            float e2 = expf(v2 - mx), e3 = expf(v3 - mx);
            float sum = (e0 + e1) + (e2 + e3);
#pragma unroll
            for (int s = 1; s < 16; s <<= 1) sum += __shfl_xor(sum, s, 16);
            float ls = logf(sum) + mx;
            float4 o = make_float4(v0 - ls, v1 - ls, v2 - ls, v3 - ls);
            *(float4*)&logits[(size_t)r * 64 + tx * 4] = o;
        }
    }
}

// ---------------- launch ----------------

extern "C" void kernel_launch(void* const* d_in, const int* in_sizes, int n_in,
                              void* d_out, int out_size, void* d_ws, size_t ws_size,
                              hipStream_t stream) {
    const float* x    = (const float*)d_in[0];
    const int*   ei   = (const int*)d_in[1];
    const float* W[4] = {(const float*)d_in[2], (const float*)d_in[4],
                         (const float*)d_in[6], (const float*)d_in[8]};
    const float* b[4] = {(const float*)d_in[3], (const float*)d_in[5],
                         (const float*)d_in[7], (const float*)d_in[9]};
    const float* linW = (const float*)d_in[10];
    const float* linb = (const float*)d_in[11];
    float* out = (float*)d_out;

    char* wp = (char*)d_ws;
    auto alloc = [&](size_t bytes) {
        void* p = (void*)wp;
        wp += (bytes + 255) & ~(size_t)255;
        return p;
    };
    int*   flag   = (int*)  alloc(4);
    int*   deg    = (int*)  alloc((size_t)NN * 4);
    float* dinv   = (float*)alloc((size_t)NN * 4);
    int*   rowptr = (int*)  alloc((size_t)(NN + 1) * 4);
    int*   cursor = (int*)  alloc((size_t)NN * 4);
    int*   bsum   = (int*)  alloc(512);
    int*   boff   = (int*)  alloc(512);
    int*   csr    = (int*)  alloc((size_t)NTOT * 4);
    unsigned short* WT  = (unsigned short*)alloc((size_t)4 * 128 * 128 * 2);
    unsigned short* WjT = (unsigned short*)alloc((size_t)4 * 64 * 128 * 2);
    unsigned short* bufM = (unsigned short*)alloc((size_t)NN * 128 * 2); // bf16 messages
    float* bufB   = (float*)alloc((size_t)NN * HF * 4);
    float* bufC   = (float*)alloc((size_t)NN * HF * 4);

    dim3 blk(256);
    k_init   <<<391, blk, 0, stream>>>(flag, deg);
    k_prep   <<<384, blk, 0, stream>>>(W[0], W[1], W[2], W[3], linW, WT, WjT);
    k_detect <<<1024, blk, 0, stream>>>(ei, flag);
    k_hist   <<<6250, blk, 0, stream>>>(ei, flag, deg);
    k_scanA  <<<98, blk, 0, stream>>>(deg, rowptr, bsum, dinv);
    k_scanB  <<<1, dim3(128), 0, stream>>>(bsum, boff, rowptr);
    k_scanC  <<<391, blk, 0, stream>>>(rowptr, boff, cursor);
    k_scatter<<<6641, blk, 0, stream>>>(ei, flag, cursor, csr);

    const float* lin[4]  = {x, bufB, bufC, bufB};
    float*       lout[4] = {bufB, bufC, bufB, bufC};
    for (int l = 0; l < 4; ++l) {
        const unsigned short* wjt = (l == 0) ? nullptr : WjT + (size_t)(l - 1) * 64 * 128;
        k_mmf<<<1563, blk, 0, stream>>>(lin[l], WT + (size_t)l * 128 * 128, dinv,
                                        wjt, linb, out, l == 1 ? 1 : 0, bufM);
        k_agg<<<25000, blk, 0, stream>>>(rowptr, csr, (const uint4*)bufM, dinv,
                                         b[l], lout[l]);
    }
    k_jk_lsm<<<1563, blk, 0, stream>>>(lout[3], linW + (size_t)3 * 128 * 64, out);
}

// Round 8
// 607.252 us; speedup vs baseline: 2.3790x; 1.1432x over previous
//
#include <hip/hip_runtime.h>
#include <cstdint>
#include <cstddef>

#define NN 100000
#define NE 1600000
#define NTOT (NE + NN)      // 1700000 edges incl self-loops
#define HF 128
#define OF 64
#define SHARD 12500         // NN/8 dst-range per XCD
#define EPB 1924            // edges per chunk: 832*1924 >= NE
#define NPB 16              // shard nodes per chunk: 832*16 >= SHARD

typedef short bfrag_t __attribute__((ext_vector_type(8)));   // 8 bf16 = 4 VGPR
typedef float f4v     __attribute__((ext_vector_type(4)));   // MFMA acc

// ---------------- helpers ----------------

__device__ __forceinline__ unsigned int f2bf_rne(float f) {
    unsigned int u = __float_as_uint(f);
    return (u + 0x7fffu + ((u >> 16) & 1u)) >> 16;
}
__device__ __forceinline__ unsigned int pack_bf2(float lo, float hi) {
    return f2bf_rne(lo) | (f2bf_rne(hi) << 16);
}

// ---------------- graph preprocessing ----------------

__global__ __launch_bounds__(256) void k_init(int* flag, int* deg) {
    int i = blockIdx.x * 256 + threadIdx.x;
    if (i == 0) *flag = 0;
    if (i < NN) deg[i] = 1;   // self-loop
}

// OR-reduce odd 32-bit words of edge_index: all zero <=> data is int64.
__global__ __launch_bounds__(256) void k_detect(const int* ei, int* flag) {
    int t = blockIdx.x * blockDim.x + threadIdx.x;
    int v = 0;
    for (int i = t; i < NE; i += gridDim.x * blockDim.x) v |= ei[2 * i + 1];
    unsigned long long b = __ballot(v != 0);
    if ((threadIdx.x & 63) == 0 && b) atomicOr(flag, 1);
}

__device__ __forceinline__ int edge_src(const int* ei, int e, bool is64) {
    return is64 ? ei[2 * e] : ei[e];
}
__device__ __forceinline__ int edge_dst(const int* ei, int e, bool is64) {
    return is64 ? ei[2 * (NE + e)] : ei[NE + e];
}

// histogram + per-edge rank (rank 0 reserved for the self-loop via deg init=1)
__global__ __launch_bounds__(256) void k_histr(const int* ei, const int* flag,
                                               int* deg, int* rank) {
    int e = blockIdx.x * 256 + threadIdx.x;
    if (e >= NE) return;
    bool is64 = (*flag) == 0;
    rank[e] = atomicAdd(&deg[edge_dst(ei, e, is64)], 1);
}

// exclusive scan of deg[N] -> rowptr (partial), also dinv = rsqrt(deg)
__global__ __launch_bounds__(256) void k_scanA(const int* deg, int* rowptr, int* bsum,
                                               float* dinv) {
    __shared__ int sh[256];
    int tid = threadIdx.x;
    int base = blockIdx.x * 1024 + tid * 4;
    int v0 = 0, v1 = 0, v2 = 0, v3 = 0;
    if (base + 0 < NN) v0 = deg[base + 0];
    if (base + 1 < NN) v1 = deg[base + 1];
    if (base + 2 < NN) v2 = deg[base + 2];
    if (base + 3 < NN) v3 = deg[base + 3];
    if (base + 0 < NN) dinv[base + 0] = rsqrtf((float)v0);
    if (base + 1 < NN) dinv[base + 1] = rsqrtf((float)v1);
    if (base + 2 < NN) dinv[base + 2] = rsqrtf((float)v2);
    if (base + 3 < NN) dinv[base + 3] = rsqrtf((float)v3);
    int s = v0 + v1 + v2 + v3;
    sh[tid] = s;
    __syncthreads();
    for (int off = 1; off < 256; off <<= 1) {
        int t = (tid >= off) ? sh[tid - off] : 0;
        __syncthreads();
        sh[tid] += t;
        __syncthreads();
    }
    int run = sh[tid] - s;
    if (base + 0 < NN) rowptr[base + 0] = run; run += v0;
    if (base + 1 < NN) rowptr[base + 1] = run; run += v1;
    if (base + 2 < NN) rowptr[base + 2] = run; run += v2;
    if (base + 3 < NN) rowptr[base + 3] = run;
    if (tid == 255) bsum[blockIdx.x] = sh[255];
}

__global__ __launch_bounds__(128) void k_scanB(const int* bsum, int* boff, int* rowptr) {
    __shared__ int sh[128];
    int tid = threadIdx.x;
    int v = (tid < 98) ? bsum[tid] : 0;
    sh[tid] = v;
    __syncthreads();
    for (int off = 1; off < 128; off <<= 1) {
        int t = (tid >= off) ? sh[tid - off] : 0;
        __syncthreads();
        sh[tid] += t;
        __syncthreads();
    }
    if (tid < 98) boff[tid] = sh[tid] - v;
    if (tid == 0) rowptr[NN] = NTOT;
}

__global__ __launch_bounds__(256) void k_scanC(int* rowptr, const int* boff) {
    int i = blockIdx.x * 256 + threadIdx.x;
    if (i < NN) rowptr[i] += boff[i >> 10];
}

// XCD-sharded, atomic-free CSR fill. Block b: shard x=b%8 (round-robin
// blockIdx->XCD), chunk c=b/8. Each shard's blocks scan all edges but write
// only dst in [x*SHARD,(x+1)*SHARD) -> each XCD L2 sees only its 850 KB of csr.
__global__ __launch_bounds__(256) void k_scat2(const int* __restrict__ ei,
                                               const int* __restrict__ flag,
                                               const int* __restrict__ rank,
                                               const int* __restrict__ rowptr,
                                               int* __restrict__ csr) {
    int x = blockIdx.x & 7, c = blockIdx.x >> 3;
    bool is64 = (*flag) == 0;
    int d0 = x * SHARD;
    // self-loops for this chunk's slice of the shard (rank 0 slot)
    int nbeg = d0 + c * NPB;
    int nend = min(d0 + SHARD, nbeg + NPB);
    for (int nd = nbeg + (int)threadIdx.x; nd < nend; nd += 256)
        csr[rowptr[nd]] = nd;
    // real edges (rank >= 1)
    int ebeg = c * EPB;
    int eend = min(NE, ebeg + EPB);
    for (int e = ebeg + (int)threadIdx.x; e < eend; e += 256) {
        int d = edge_dst(ei, e, is64);
        if ((unsigned)(d - d0) < SHARD) {
            int s = edge_src(ei, e, is64);
            csr[rowptr[d] + rank[e]] = s;
        }
    }
}

// ---------------- weight prep: bf16 + transpose to [n][k] ----------------
__global__ __launch_bounds__(256) void k_prep(const float* __restrict__ W0,
                                              const float* __restrict__ W1,
                                              const float* __restrict__ W2,
                                              const float* __restrict__ W3,
                                              const float* __restrict__ linW,
                                              unsigned short* __restrict__ WT,
                                              unsigned short* __restrict__ WjT) {
    int idx = blockIdx.x * 256 + threadIdx.x;
    if (idx < 4 * 128 * 128) {
        int l = idx >> 14, r = idx & 16383, n = r >> 7, k = r & 127;
        const float* Wl = (l == 0) ? W0 : (l == 1) ? W1 : (l == 2) ? W2 : W3;
        WT[idx] = (unsigned short)f2bf_rne(Wl[k * 128 + n]);
    } else if (idx < 4 * 128 * 128 + 4 * 64 * 128) {
        int i2 = idx - 65536;
        int l = i2 >> 13, r = i2 & 8191, n = r >> 7, k = r & 127;
        WjT[i2] = (unsigned short)f2bf_rne(linW[(size_t)(l * 128 + k) * 64 + n]);
    }
}

// ---------------- MFMA matmul + fused JK ----------------
__global__ __launch_bounds__(256) void k_mmf(const float* __restrict__ A,
                                             const unsigned short* __restrict__ WT,
                                             const float* __restrict__ dinv,
                                             const unsigned short* __restrict__ WjT,
                                             const float* __restrict__ linb,
                                             float* __restrict__ logits, int first,
                                             unsigned short* __restrict__ m16) {
    __shared__ unsigned short Alds[64 * 128];    // 16 KB
    __shared__ unsigned short Wlds[128 * 128];   // 32 KB
    __shared__ unsigned short Wjlds[64 * 128];   // 16 KB
    int tid = threadIdx.x;
    int row0 = blockIdx.x * 64;
    bool has_jk = (WjT != nullptr);

    for (int c = tid; c < 2048; c += 256) {       // W^T, swizzled
        int row = c >> 4, c16 = c & 15;
        uint4 v = *(const uint4*)&WT[row * 128 + c16 * 8];
        *(uint4*)((char*)Wlds + row * 256 + ((c16 * 16) ^ ((row & 7) << 4))) = v;
    }
    if (has_jk) {
        for (int c = tid; c < 1024; c += 256) {
            int row = c >> 4, c16 = c & 15;
            uint4 v = *(const uint4*)&WjT[row * 128 + c16 * 8];
            *(uint4*)((char*)Wjlds + row * 256 + ((c16 * 16) ^ ((row & 7) << 4))) = v;
        }
    }
    {
        int row = tid >> 2, gr = row0 + row;      // A f32->bf16, swizzled
#pragma unroll
        for (int j = 0; j < 4; ++j) {
            int c8 = (tid & 3) * 4 + j;
            float4 v0 = make_float4(0.f, 0.f, 0.f, 0.f);
            float4 v1 = make_float4(0.f, 0.f, 0.f, 0.f);
            if (gr < NN) {
                v0 = *(const float4*)&A[(size_t)gr * 128 + c8 * 8];
                v1 = *(const float4*)&A[(size_t)gr * 128 + c8 * 8 + 4];
            }
            uint4 o;
            o.x = pack_bf2(v0.x, v0.y);
            o.y = pack_bf2(v0.z, v0.w);
            o.z = pack_bf2(v1.x, v1.y);
            o.w = pack_bf2(v1.z, v1.w);
            *(uint4*)((char*)Alds + row * 256 + ((c8 * 16) ^ ((row & 7) << 4))) = o;
        }
    }
    __syncthreads();

    int lane = tid & 63, w = tid >> 6;
    int r15 = lane & 15, q = lane >> 4;
    int xo = (r15 & 7) << 4;

    f4v acc[8], accj[4];
#pragma unroll
    for (int i = 0; i < 8; ++i) acc[i] = (f4v){0.f, 0.f, 0.f, 0.f};
#pragma unroll
    for (int i = 0; i < 4; ++i) accj[i] = (f4v){0.f, 0.f, 0.f, 0.f};

#pragma unroll
    for (int ks = 0; ks < 4; ++ks) {
        int ko = ks * 64 + q * 16;
        bfrag_t a = *(const bfrag_t*)((const char*)Alds + (16 * w + r15) * 256 + (ko ^ xo));
#pragma unroll
        for (int nb = 0; nb < 8; ++nb) {
            bfrag_t b = *(const bfrag_t*)((const char*)Wlds + (nb * 16 + r15) * 256 + (ko ^ xo));
            acc[nb] = __builtin_amdgcn_mfma_f32_16x16x32_bf16(a, b, acc[nb], 0, 0, 0);
        }
        if (has_jk) {
#pragma unroll
            for (int jb = 0; jb < 4; ++jb) {
                bfrag_t b = *(const bfrag_t*)((const char*)Wjlds + (jb * 16 + r15) * 256 + (ko ^ xo));
                accj[jb] = __builtin_amdgcn_mfma_f32_16x16x32_bf16(a, b, accj[jb], 0, 0, 0);
            }
        }
    }

#pragma unroll
    for (int reg = 0; reg < 4; ++reg) {
        int gr = row0 + 16 * w + q * 4 + reg;
        if (gr < NN) {
            float sc = dinv[gr];
#pragma unroll
            for (int nb = 0; nb < 8; ++nb)
                m16[(size_t)gr * 128 + nb * 16 + r15] =
                    (unsigned short)f2bf_rne(acc[nb][reg] * sc);
            if (has_jk) {
#pragma unroll
                for (int jb = 0; jb < 4; ++jb) {
                    size_t off = (size_t)gr * 64 + jb * 16 + r15;
                    float prev = first ? linb[jb * 16 + r15] : logits[off];
                    logits[off] = prev + accj[jb][reg];
                }
            }
        }
    }
}

// h_out[d][:] = relu(dinv[d] * sum_{s in N(d)} bf16m[s][:] + b)
// one wave per node; 4 groups of 16 lanes; 16-edge inner step = 4 independent
// uint4 gathers in flight. All __shfl executed by ALL lanes (wave-uniform).
__global__ __launch_bounds__(256) void k_agg(const int* __restrict__ rowptr,
                                             const int* __restrict__ csr,
                                             const uint4* __restrict__ m4,
                                             const float* __restrict__ dinv,
                                             const float* __restrict__ bias,
                                             float* __restrict__ out) {
    int w = threadIdx.x >> 6, lane = threadIdx.x & 63;
    int grp = lane >> 4, lj = lane & 15;
    int node = blockIdx.x * 4 + w;
    if (node >= NN) return;
    int beg = rowptr[node], end = rowptr[node + 1];

    float a[8];
#pragma unroll
    for (int q = 0; q < 8; ++q) a[q] = 0.f;

    auto acc8 = [&](uint4 v) {
        a[0] += __uint_as_float(v.x << 16);
        a[1] += __uint_as_float(v.x & 0xffff0000u);
        a[2] += __uint_as_float(v.y << 16);
        a[3] += __uint_as_float(v.y & 0xffff0000u);
        a[4] += __uint_as_float(v.z << 16);
        a[5] += __uint_as_float(v.z & 0xffff0000u);
        a[6] += __uint_as_float(v.w << 16);
        a[7] += __uint_as_float(v.w & 0xffff0000u);
    };

    for (int base = beg; base < end; base += 64) {
        int cnt = min(64, end - base);
        int sv = (lane < cnt) ? csr[base + lane] : 0;
        int k = 0;
        for (; k + 16 <= cnt; k += 16) {
            int s0 = __shfl(sv, k + grp);
            int s1 = __shfl(sv, k + 4 + grp);
            int s2 = __shfl(sv, k + 8 + grp);
            int s3 = __shfl(sv, k + 12 + grp);
            uint4 v0 = m4[(size_t)s0 * 16 + lj];
            uint4 v1 = m4[(size_t)s1 * 16 + lj];
            uint4 v2 = m4[(size_t)s2 * 16 + lj];
            uint4 v3 = m4[(size_t)s3 * 16 + lj];
            acc8(v0); acc8(v1); acc8(v2); acc8(v3);
        }
        for (; k + 4 <= cnt; k += 4) {      // wave-uniform
            int s = __shfl(sv, k + grp);
            uint4 v = m4[(size_t)s * 16 + lj];
            acc8(v);
        }
        int rem = cnt - k;                  // 0..3
        if (rem) {                          // wave-uniform
            int idx = k + grp;
            if (idx >= cnt) idx = cnt - 1;  // clamp; shuffle by ALL lanes
            int s = __shfl(sv, idx);
            if (grp < rem) {                // only accumulate predicated
                uint4 v = m4[(size_t)s * 16 + lj];
                acc8(v);
            }
        }
    }
#pragma unroll
    for (int q = 0; q < 8; ++q) a[q] += __shfl_xor(a[q], 16);
#pragma unroll
    for (int q = 0; q < 8; ++q) a[q] += __shfl_xor(a[q], 32);

    float sc = dinv[node];
    if (grp == 0) {
        float4 bb = ((const float4*)bias)[lj * 2];
        float4 o = make_float4(fmaxf(a[0] * sc + bb.x, 0.f),
                               fmaxf(a[1] * sc + bb.y, 0.f),
                               fmaxf(a[2] * sc + bb.z, 0.f),
                               fmaxf(a[3] * sc + bb.w, 0.f));
        *(float4*)&out[(size_t)node * 128 + lj * 8] = o;
    } else if (grp == 1) {
        float4 bb = ((const float4*)bias)[lj * 2 + 1];
        float4 o = make_float4(fmaxf(a[4] * sc + bb.x, 0.f),
                               fmaxf(a[5] * sc + bb.y, 0.f),
                               fmaxf(a[6] * sc + bb.z, 0.f),
                               fmaxf(a[7] * sc + bb.w, 0.f));
        *(float4*)&out[(size_t)node * 128 + lj * 8 + 4] = o;
    }
}

// Final: logits[r][:] += H[r][:] @ Wl; then in-place log_softmax (width-16 shfl).
__global__ __launch_bounds__(256) void k_jk_lsm(const float* __restrict__ Hl,
                                                const float* __restrict__ Wl,
                                                float* __restrict__ logits) {
    __shared__ float At[32][68];
    __shared__ float Wt[32][64];
    int tid = threadIdx.x;
    int tx = tid & 15, ty = tid >> 4;
    int row0 = blockIdx.x * 64;
    float acc[4][4];
#pragma unroll
    for (int j = 0; j < 4; ++j)
#pragma unroll
        for (int c = 0; c < 4; ++c) acc[j][c] = 0.f;

    for (int kb = 0; kb < 128; kb += 32) {
#pragma unroll
        for (int i = 0; i < 2; ++i) {
            int kr = ty + i * 16;
            float4 wv = *(const float4*)&Wl[(size_t)(kb + kr) * 64 + tx * 4];
            *(float4*)&Wt[kr][tx * 4] = wv;
        }
#pragma unroll
        for (int i = 0; i < 2; ++i) {
            int idx = tid + i * 256;
            int r = idx >> 3, c4 = idx & 7;
            int gr = row0 + r;
            float4 v = make_float4(0.f, 0.f, 0.f, 0.f);
            if (gr < NN) v = *(const float4*)&Hl[(size_t)gr * 128 + kb + c4 * 4];
            At[c4 * 4 + 0][r] = v.x;
            At[c4 * 4 + 1][r] = v.y;
            At[c4 * 4 + 2][r] = v.z;
            At[c4 * 4 + 3][r] = v.w;
        }
        __syncthreads();
#pragma unroll 4
        for (int k = 0; k < 32; ++k) {
            float4 a4 = *(const float4*)&At[k][ty * 4];
            float4 wv = *(const float4*)&Wt[k][tx * 4];
            float a[4] = {a4.x, a4.y, a4.z, a4.w};
#pragma unroll
            for (int j = 0; j < 4; ++j) {
                acc[j][0] += a[j] * wv.x;
                acc[j][1] += a[j] * wv.y;
                acc[j][2] += a[j] * wv.z;
                acc[j][3] += a[j] * wv.w;
            }
        }
        __syncthreads();
    }
#pragma unroll
    for (int j = 0; j < 4; ++j) {
        int r = row0 + ty * 4 + j;
        if (r < NN) {
            float4 prev = *(const float4*)&logits[(size_t)r * 64 + tx * 4];
            float v0 = prev.x + acc[j][0];
            float v1 = prev.y + acc[j][1];
            float v2 = prev.z + acc[j][2];
            float v3 = prev.w + acc[j][3];
            float mx = fmaxf(fmaxf(v0, v1), fmaxf(v2, v3));
#pragma unroll
            for (int s = 1; s < 16; s <<= 1) mx = fmaxf(mx, __shfl_xor(mx, s, 16));
            float e0 = expf(v0 - mx), e1 = expf(v1 - mx);
            float e2 = expf(v2 - mx), e3 = expf(v3 - mx);
            float sum = (e0 + e1) + (e2 + e3);
#pragma unroll
            for (int s = 1; s < 16; s <<= 1) sum += __shfl_xor(sum, s, 16);
            float ls = logf(sum) + mx;
            float4 o = make_float4(v0 - ls, v1 - ls, v2 - ls, v3 - ls);
            *(float4*)&logits[(size_t)r * 64 + tx * 4] = o;
        }
    }
}

// ---------------- launch ----------------

extern "C" void kernel_launch(void* const* d_in, const int* in_sizes, int n_in,
                              void* d_out, int out_size, void* d_ws, size_t ws_size,
                              hipStream_t stream) {
    const float* x    = (const float*)d_in[0];
    const int*   ei   = (const int*)d_in[1];
    const float* W[4] = {(const float*)d_in[2], (const float*)d_in[4],
                         (const float*)d_in[6], (const float*)d_in[8]};
    const float* b[4] = {(const float*)d_in[3], (const float*)d_in[5],
                         (const float*)d_in[7], (const float*)d_in[9]};
    const float* linW = (const float*)d_in[10];
    const float* linb = (const float*)d_in[11];
    float* out = (float*)d_out;

    char* wp = (char*)d_ws;
    auto alloc = [&](size_t bytes) {
        void* p = (void*)wp;
        wp += (bytes + 255) & ~(size_t)255;
        return p;
    };
    int*   flag   = (int*)  alloc(4);
    int*   deg    = (int*)  alloc((size_t)NN * 4);
    float* dinv   = (float*)alloc((size_t)NN * 4);
    int*   rowptr = (int*)  alloc((size_t)(NN + 1) * 4);
    int*   rank   = (int*)  alloc((size_t)NE * 4);
    int*   bsum   = (int*)  alloc(512);
    int*   boff   = (int*)  alloc(512);
    int*   csr    = (int*)  alloc((size_t)NTOT * 4);
    unsigned short* WT  = (unsigned short*)alloc((size_t)4 * 128 * 128 * 2);
    unsigned short* WjT = (unsigned short*)alloc((size_t)4 * 64 * 128 * 2);
    unsigned short* bufM = (unsigned short*)alloc((size_t)NN * 128 * 2);
    float* bufB   = (float*)alloc((size_t)NN * HF * 4);
    float* bufC   = (float*)alloc((size_t)NN * HF * 4);

    dim3 blk(256);
    k_init   <<<391, blk, 0, stream>>>(flag, deg);
    k_prep   <<<384, blk, 0, stream>>>(W[0], W[1], W[2], W[3], linW, WT, WjT);
    k_detect <<<1024, blk, 0, stream>>>(ei, flag);
    k_histr  <<<6250, blk, 0, stream>>>(ei, flag, deg, rank);
    k_scanA  <<<98, blk, 0, stream>>>(deg, rowptr, bsum, dinv);
    k_scanB  <<<1, dim3(128), 0, stream>>>(bsum, boff, rowptr);
    k_scanC  <<<391, blk, 0, stream>>>(rowptr, boff);
    k_scat2  <<<6656, blk, 0, stream>>>(ei, flag, rank, rowptr, csr);

    const float* lin[4]  = {x, bufB, bufC, bufB};
    float*       lout[4] = {bufB, bufC, bufB, bufC};
    for (int l = 0; l < 4; ++l) {
        const unsigned short* wjt = (l == 0) ? nullptr : WjT + (size_t)(l - 1) * 64 * 128;
        k_mmf<<<1563, blk, 0, stream>>>(lin[l], WT + (size_t)l * 128 * 128, dinv,
                                        wjt, linb, out, l == 1 ? 1 : 0, bufM);
        k_agg<<<25000, blk, 0, stream>>>(rowptr, csr, (const uint4*)bufM, dinv,
                                         b[l], lout[l]);
    }
    k_jk_lsm<<<1563, blk, 0, stream>>>(lout[3], linW + (size_t)3 * 128 * 64, out);
}